// Round 2
// baseline (501.101 us; speedup 1.0000x reference)
//
#include <hip/hip_runtime.h>
#include <hip/hip_bf16.h>
#include <stdint.h>

#define KDIM 1024
#define NPAD 416                    // 26 col-tiles of 16 (405 real cols + 11 pad)
#define NCOLS 405
#define SCORE_COLS 81
#define BBOX_COLS 324
#define NROWS 65536
#define FDIM 300
#define SLAB (NPAD * 32)            // bf16 elems per 32-k block = 13312

// Blocked Wt layout: element (row, k) -> (k>>5)*SLAB + row*32 + (k&31)
// i.e. [kt][416 cols][32 k]; a wave's 16-col fragment is a coalesced 1 KB chunk.

typedef short v8s __attribute__((ext_vector_type(8)));
typedef float v4f __attribute__((ext_vector_type(4)));

__device__ __forceinline__ uint16_t f2bf(float f) {
    union { float f; uint32_t u; } c; c.f = f;
    uint32_t r = c.u + 0x7FFFu + ((c.u >> 16) & 1u);
    return (uint16_t)(r >> 16);
}

__device__ __forceinline__ size_t wt_off(int row, int k) {
    return (size_t)(k >> 5) * SLAB + (size_t)row * 32 + (k & 31);
}

// ---- prep: W_total rows 0 (cls), 81..404 (bbox), 405..415 (zero pad) + biases
__global__ void fill_w(const float* __restrict__ Wcls, const float* __restrict__ bcls,
                       const float* __restrict__ Wbbox, const float* __restrict__ bbbox,
                       uint16_t* __restrict__ Wt, float* __restrict__ bt) {
    int idx = blockIdx.x * 256 + threadIdx.x;        // NPAD*1024 total
    int row = idx >> 10, k = idx & 1023;
    if (!(row >= 1 && row < 81)) {                   // rows 1..80 done by fill_w_sem
        float v;
        if (row == 0) v = Wcls[k];
        else if (row < 81 + BBOX_COLS) v = Wbbox[(size_t)(row - 81) * KDIM + k];
        else v = 0.f;
        Wt[wt_off(row, k)] = f2bf(v);
    }
    if (k == 0 && !(row >= 1 && row < 81)) {
        float b;
        if (row == 0) b = bcls[0];
        else if (row < 81 + BBOX_COLS) b = bbbox[row - 81];
        else b = 0.f;
        bt[row] = b;
    }
}

// ---- prep: W_total rows 1..80 = (8/||sem_row||) * (sem_row @ W_sem)
__global__ void fill_w_sem(const float* __restrict__ Wsem, const float* __restrict__ bsem,
                           const float* __restrict__ semm,
                           uint16_t* __restrict__ Wt, float* __restrict__ bt) {
    const int n = blockIdx.x;          // 0..79
    const int kq = blockIdx.y;         // 0..3
    const int tid = threadIdx.x;       // 256
    __shared__ float s_row[FDIM];
    __shared__ float red[256];
    __shared__ float s_scale, s_bdot;

    const float* sr = semm + (size_t)n * FDIM;
    float p = 0.f, pb = 0.f;
    for (int f = tid; f < FDIM; f += 256) {
        float v = sr[f];
        s_row[f] = v;
        p += v * v;
        pb += v * bsem[f];
    }
    red[tid] = p; __syncthreads();
    for (int s = 128; s > 0; s >>= 1) { if (tid < s) red[tid] += red[tid + s]; __syncthreads(); }
    float norm2 = red[0]; __syncthreads();
    red[tid] = pb; __syncthreads();
    for (int s = 128; s > 0; s >>= 1) { if (tid < s) red[tid] += red[tid + s]; __syncthreads(); }
    if (tid == 0) { s_scale = 8.0f / sqrtf(norm2); s_bdot = red[0]; }
    __syncthreads();
    const float scale = s_scale;
    if (kq == 0 && tid == 0) bt[1 + n] = scale * s_bdot;

    const int k = kq * 256 + tid;      // exactly one k per thread
    float acc = 0.f;
    #pragma unroll 8
    for (int f = 0; f < FDIM; ++f) acc += s_row[f] * Wsem[(size_t)f * KDIM + k];
    Wt[wt_off(1 + n, k)] = f2bf(scale * acc);
}

// ---- fused GEMM: one block = 64 rows x ALL 416 cols (x read exactly once)
// B fragments: direct L2->VGPR (no LDS), reloaded right after last use.
// A: fp32->bf16 reg-staged into LDS, prefetch depth 2 over 3 buffers.
// MAIN BODY IS FULLY UNIFORM: no conditional loads -> compiler emits counted
// vmcnt (never vmcnt(0)); the VMEM queue never drains. Tail iters peeled.
// Waves 6/7 compute clamped (dummy) tiles; epilogue masks them.
#define A_STRIDE 36                     // bf16 elems per A row in LDS (bank-friendly)
#define A_BUF_ELEMS (64 * A_STRIDE)     // 2304
#define EPS_STRIDE 409
#define SMEM_BYTES (32 * EPS_STRIDE * 4)  // 52352 >= 3*A_BUF_ELEMS*2 = 13824

__device__ __forceinline__ void stcvt(uint16_t* p, float4 av) {
    __hip_bfloat162 lo = __float22bfloat162_rn(make_float2(av.x, av.y));
    __hip_bfloat162 hi = __float22bfloat162_rn(make_float2(av.z, av.w));
    uint2 v; v.x = *(uint32_t*)&lo; v.y = *(uint32_t*)&hi;
    *(uint2*)p = v;
}

__global__ __launch_bounds__(512, 4) void gemm_fused(
        const float* __restrict__ x, const uint16_t* __restrict__ Wt,
        const float* __restrict__ bt, float* __restrict__ out) {
    const int tid = threadIdx.x;
    const int wave = tid >> 6, lane = tid & 63;
    const int quad = lane >> 4, l16 = lane & 15;
    const int mtile = blockIdx.x;
    // real col-tile count per wave (epilogue masking only): 4,4,4,4,4,4,2,0
    const int NT = (wave < 6) ? 4 : (wave == 6 ? 2 : 0);

    __shared__ __align__(16) char smem[SMEM_BYTES];
    uint16_t* As = (uint16_t*)smem;

    const float* xb = x + (size_t)mtile * 64 * KDIM;
    const int colbase = wave * 64;

    v4f acc[4][4];
    #pragma unroll
    for (int mi = 0; mi < 4; ++mi)
        #pragma unroll
        for (int ni = 0; ni < 4; ++ni)
            acc[mi][ni] = v4f{0.f, 0.f, 0.f, 0.f};

    const int am = tid >> 3, akc = tid & 7;        // A: row, float4-chunk
    const float* aptr = xb + (size_t)am * KDIM + akc * 4;          // +32 floats per kt

    // uniform B fragment pointers; out-of-range tiles clamp to tile 25 (dummy,
    // L2-hit loads; their accumulators are garbage and never stored)
    const uint16_t* bfrag[4];
    #pragma unroll
    for (int ni = 0; ni < 4; ++ni) {
        int t = wave * 4 + ni; if (t > 25) t = 25;
        bfrag[ni] = Wt + (size_t)(t * 16 + l16) * 32 + quad * 8;
    }

    v8s bcur[4];

    // ---- prologue: issue A(0), A(1), B(0); stage A(0) into buffer 0
    float4 av0  = *(const float4*)aptr;
    float4 av_n = *(const float4*)(aptr + 32);
    #pragma unroll
    for (int ni = 0; ni < 4; ++ni) bcur[ni] = *(const v8s*)bfrag[ni];
    stcvt(As + am * A_STRIDE + akc * 4, av0);
    asm volatile("s_waitcnt lgkmcnt(0)" ::: "memory");
    __builtin_amdgcn_s_barrier();
    asm volatile("" ::: "memory");

    // ---- main loop: kt = 0..29, fully uniform body, 1 raw barrier/iter
    int rb = 0, wb = 1;
    for (int kt = 0; kt < 30; ++kt) {
        float4 av_nn = *(const float4*)(aptr + (size_t)(kt + 2) * 32);  // A(kt+2)
        const uint16_t* Ar = As + rb * A_BUF_ELEMS;
        v8s a0 = *(const v8s*)(Ar + (0 * 16 + l16) * A_STRIDE + quad * 8);
        v8s a1 = *(const v8s*)(Ar + (1 * 16 + l16) * A_STRIDE + quad * 8);
        v8s a2 = *(const v8s*)(Ar + (2 * 16 + l16) * A_STRIDE + quad * 8);
        v8s a3 = *(const v8s*)(Ar + (3 * 16 + l16) * A_STRIDE + quad * 8);
        stcvt(As + wb * A_BUF_ELEMS + am * A_STRIDE + akc * 4, av_n);   // A(kt+1)
        av_n = av_nn;
        const size_t nxt = (size_t)(kt + 1) * SLAB;
        #pragma unroll
        for (int ni = 0; ni < 4; ++ni) {
            acc[0][ni] = __builtin_amdgcn_mfma_f32_16x16x32_bf16(a0, bcur[ni], acc[0][ni], 0, 0, 0);
            acc[1][ni] = __builtin_amdgcn_mfma_f32_16x16x32_bf16(a1, bcur[ni], acc[1][ni], 0, 0, 0);
            acc[2][ni] = __builtin_amdgcn_mfma_f32_16x16x32_bf16(a2, bcur[ni], acc[2][ni], 0, 0, 0);
            acc[3][ni] = __builtin_amdgcn_mfma_f32_16x16x32_bf16(a3, bcur[ni], acc[3][ni], 0, 0, 0);
            bcur[ni] = *(const v8s*)(bfrag[ni] + nxt);   // B(kt+1), ~1 iter of cover
        }
        asm volatile("s_waitcnt lgkmcnt(0)" ::: "memory");
        __builtin_amdgcn_s_barrier();
        asm volatile("" ::: "memory");
        int ib = 3 - rb - wb; rb = wb; wb = ib;
    }

    // ---- kt = 30 (peeled: no A(kt+2) prefetch)
    {
        const uint16_t* Ar = As + rb * A_BUF_ELEMS;
        v8s a0 = *(const v8s*)(Ar + (0 * 16 + l16) * A_STRIDE + quad * 8);
        v8s a1 = *(const v8s*)(Ar + (1 * 16 + l16) * A_STRIDE + quad * 8);
        v8s a2 = *(const v8s*)(Ar + (2 * 16 + l16) * A_STRIDE + quad * 8);
        v8s a3 = *(const v8s*)(Ar + (3 * 16 + l16) * A_STRIDE + quad * 8);
        stcvt(As + wb * A_BUF_ELEMS + am * A_STRIDE + akc * 4, av_n);   // A(31)
        const size_t nxt = (size_t)31 * SLAB;
        #pragma unroll
        for (int ni = 0; ni < 4; ++ni) {
            acc[0][ni] = __builtin_amdgcn_mfma_f32_16x16x32_bf16(a0, bcur[ni], acc[0][ni], 0, 0, 0);
            acc[1][ni] = __builtin_amdgcn_mfma_f32_16x16x32_bf16(a1, bcur[ni], acc[1][ni], 0, 0, 0);
            acc[2][ni] = __builtin_amdgcn_mfma_f32_16x16x32_bf16(a2, bcur[ni], acc[2][ni], 0, 0, 0);
            acc[3][ni] = __builtin_amdgcn_mfma_f32_16x16x32_bf16(a3, bcur[ni], acc[3][ni], 0, 0, 0);
            bcur[ni] = *(const v8s*)(bfrag[ni] + nxt);   // B(31)
        }
        asm volatile("s_waitcnt lgkmcnt(0)" ::: "memory");
        __builtin_amdgcn_s_barrier();
        asm volatile("" ::: "memory");
        int ib = 3 - rb - wb; rb = wb; wb = ib;
    }

    // ---- kt = 31 (peeled: compute only)
    {
        const uint16_t* Ar = As + rb * A_BUF_ELEMS;
        v8s a0 = *(const v8s*)(Ar + (0 * 16 + l16) * A_STRIDE + quad * 8);
        v8s a1 = *(const v8s*)(Ar + (1 * 16 + l16) * A_STRIDE + quad * 8);
        v8s a2 = *(const v8s*)(Ar + (2 * 16 + l16) * A_STRIDE + quad * 8);
        v8s a3 = *(const v8s*)(Ar + (3 * 16 + l16) * A_STRIDE + quad * 8);
        #pragma unroll
        for (int ni = 0; ni < 4; ++ni) {
            acc[0][ni] = __builtin_amdgcn_mfma_f32_16x16x32_bf16(a0, bcur[ni], acc[0][ni], 0, 0, 0);
            acc[1][ni] = __builtin_amdgcn_mfma_f32_16x16x32_bf16(a1, bcur[ni], acc[1][ni], 0, 0, 0);
            acc[2][ni] = __builtin_amdgcn_mfma_f32_16x16x32_bf16(a2, bcur[ni], acc[2][ni], 0, 0, 0);
            acc[3][ni] = __builtin_amdgcn_mfma_f32_16x16x32_bf16(a3, bcur[ni], acc[3][ni], 0, 0, 0);
        }
    }

    // ---- epilogue: stage through LDS (full-line coalesced, nontemporal stores)
    const int rowbase = mtile * 64;
    float* eps = (float*)smem;
    float* outb = out + (size_t)NROWS * SCORE_COLS;
    float bias[4];
    #pragma unroll
    for (int ni = 0; ni < 4; ++ni)
        bias[ni] = (ni < NT) ? bt[colbase + ni * 16 + l16] : 0.f;
    #pragma unroll
    for (int h = 0; h < 2; ++h) {
        __syncthreads();                       // LDS free for reuse / prev half done
        #pragma unroll
        for (int mi2 = 0; mi2 < 2; ++mi2) {
            const int mi = h * 2 + mi2;
            #pragma unroll
            for (int ni = 0; ni < 4; ++ni) {
                const int col = colbase + ni * 16 + l16;
                if (ni < NT && col < NCOLS) {
                    #pragma unroll
                    for (int r = 0; r < 4; ++r)
                        eps[(mi2 * 16 + quad * 4 + r) * EPS_STRIDE + col] = acc[mi][ni][r] + bias[ni];
                }
            }
        }
        __syncthreads();
        const int row0 = rowbase + h * 32;
        for (int idx = tid; idx < 32 * SCORE_COLS; idx += 512) {
            int r = idx / SCORE_COLS, c = idx - r * SCORE_COLS;
            __builtin_nontemporal_store(eps[r * EPS_STRIDE + c],
                                        &out[(size_t)(row0 + r) * SCORE_COLS + c]);
        }
        for (int idx = tid; idx < 32 * BBOX_COLS; idx += 512) {
            int r = idx / BBOX_COLS, c = idx - r * BBOX_COLS;
            __builtin_nontemporal_store(eps[r * EPS_STRIDE + SCORE_COLS + c],
                                        &outb[(size_t)(row0 + r) * BBOX_COLS + c]);
        }
    }
}

extern "C" void kernel_launch(void* const* d_in, const int* in_sizes, int n_in,
                              void* d_out, int out_size, void* d_ws, size_t ws_size,
                              hipStream_t stream) {
    const float* x     = (const float*)d_in[0];
    const float* Wcls  = (const float*)d_in[1];
    const float* bcls  = (const float*)d_in[2];
    const float* Wsem  = (const float*)d_in[3];
    const float* bsem  = (const float*)d_in[4];
    const float* Wbbox = (const float*)d_in[5];
    const float* bbbox = (const float*)d_in[6];
    const float* semm  = (const float*)d_in[7];
    float* out = (float*)d_out;

    uint16_t* Wt = (uint16_t*)d_ws;                                  // 416*1024*2 = 832 KB (blocked)
    float*    bt = (float*)((char*)d_ws + (size_t)NPAD * KDIM * 2);  // 1.7 KB

    fill_w<<<dim3((NPAD * KDIM) / 256), dim3(256), 0, stream>>>(Wcls, bcls, Wbbox, bbbox, Wt, bt);
    fill_w_sem<<<dim3(80, 4), dim3(256), 0, stream>>>(Wsem, bsem, semm, Wt, bt);
    gemm_fused<<<dim3(NROWS / 64), dim3(512), 0, stream>>>(x, Wt, bt, out);
}

// Round 4
// 489.700 us; speedup vs baseline: 1.0233x; 1.0233x over previous
//
#include <hip/hip_runtime.h>
#include <hip/hip_bf16.h>
#include <stdint.h>

#define KDIM 1024
#define NPAD 416                    // 26 col-tiles of 16 (405 real cols + 11 pad)
#define NCOLS 405
#define SCORE_COLS 81
#define BBOX_COLS 324
#define NROWS 65536
#define FDIM 300
#define SLAB (NPAD * 32)            // bf16 elems per 32-k block = 13312

// Blocked Wt layout: element (row, k) -> (k>>5)*SLAB + row*32 + (k&31)
// i.e. [kt][416 cols][32 k]; a wave's 16-col fragment is a coalesced 1 KB chunk.

typedef short v8s __attribute__((ext_vector_type(8)));
typedef float v4f __attribute__((ext_vector_type(4)));

__device__ __forceinline__ uint16_t f2bf(float f) {
    union { float f; uint32_t u; } c; c.f = f;
    uint32_t r = c.u + 0x7FFFu + ((c.u >> 16) & 1u);
    return (uint16_t)(r >> 16);
}

__device__ __forceinline__ size_t wt_off(int row, int k) {
    return (size_t)(k >> 5) * SLAB + (size_t)row * 32 + (k & 31);
}

// ---- prep: W_total rows 0 (cls), 81..404 (bbox), 405..415 (zero pad) + biases
__global__ void fill_w(const float* __restrict__ Wcls, const float* __restrict__ bcls,
                       const float* __restrict__ Wbbox, const float* __restrict__ bbbox,
                       uint16_t* __restrict__ Wt, float* __restrict__ bt) {
    int idx = blockIdx.x * 256 + threadIdx.x;        // NPAD*1024 total
    int row = idx >> 10, k = idx & 1023;
    if (!(row >= 1 && row < 81)) {                   // rows 1..80 done by fill_w_sem
        float v;
        if (row == 0) v = Wcls[k];
        else if (row < 81 + BBOX_COLS) v = Wbbox[(size_t)(row - 81) * KDIM + k];
        else v = 0.f;
        Wt[wt_off(row, k)] = f2bf(v);
    }
    if (k == 0 && !(row >= 1 && row < 81)) {
        float b;
        if (row == 0) b = bcls[0];
        else if (row < 81 + BBOX_COLS) b = bbbox[row - 81];
        else b = 0.f;
        bt[row] = b;
    }
}

// ---- prep: W_total rows 1..80 = (8/||sem_row||) * (sem_row @ W_sem)
__global__ void fill_w_sem(const float* __restrict__ Wsem, const float* __restrict__ bsem,
                           const float* __restrict__ semm,
                           uint16_t* __restrict__ Wt, float* __restrict__ bt) {
    const int n = blockIdx.x;          // 0..79
    const int kq = blockIdx.y;         // 0..3
    const int tid = threadIdx.x;       // 256
    __shared__ float s_row[FDIM];
    __shared__ float red[256];
    __shared__ float s_scale, s_bdot;

    const float* sr = semm + (size_t)n * FDIM;
    float p = 0.f, pb = 0.f;
    for (int f = tid; f < FDIM; f += 256) {
        float v = sr[f];
        s_row[f] = v;
        p += v * v;
        pb += v * bsem[f];
    }
    red[tid] = p; __syncthreads();
    for (int s = 128; s > 0; s >>= 1) { if (tid < s) red[tid] += red[tid + s]; __syncthreads(); }
    float norm2 = red[0]; __syncthreads();
    red[tid] = pb; __syncthreads();
    for (int s = 128; s > 0; s >>= 1) { if (tid < s) red[tid] += red[tid + s]; __syncthreads(); }
    if (tid == 0) { s_scale = 8.0f / sqrtf(norm2); s_bdot = red[0]; }
    __syncthreads();
    const float scale = s_scale;
    if (kq == 0 && tid == 0) bt[1 + n] = scale * s_bdot;

    const int k = kq * 256 + tid;      // exactly one k per thread
    float acc = 0.f;
    #pragma unroll 8
    for (int f = 0; f < FDIM; ++f) acc += s_row[f] * Wsem[(size_t)f * KDIM + k];
    Wt[wt_off(1 + n, k)] = f2bf(scale * acc);
}

// ---- fused GEMM: one block = 64 rows x ALL 416 cols (x read exactly once)
// B fragments: direct L2->VGPR (no LDS), reloaded right after last use.
// A: fp32->bf16 reg-staged into LDS, prefetch depth 3, A-load issued LAST in the
// iteration (after the B loads). vmcnt is FIFO: with A newest in the queue, the
// MFMA's counted wait on B never drains the HBM-latency A load, and the stcvt
// consume of A has ~2 full iterations of cover. Tail iters peeled (uniform body).
#define A_STRIDE 36                     // bf16 elems per A row in LDS (bank-friendly)
#define A_BUF_ELEMS (64 * A_STRIDE)     // 2304
#define EPS_STRIDE 409
#define SMEM_BYTES (32 * EPS_STRIDE * 4)  // 52352 >= 2*A_BUF_ELEMS*2 = 9216

__device__ __forceinline__ void stcvt(uint16_t* p, float4 av) {
    __hip_bfloat162 lo = __float22bfloat162_rn(make_float2(av.x, av.y));
    __hip_bfloat162 hi = __float22bfloat162_rn(make_float2(av.z, av.w));
    uint2 v; v.x = *(uint32_t*)&lo; v.y = *(uint32_t*)&hi;
    *(uint2*)p = v;
}

__global__ __launch_bounds__(512, 4) void gemm_fused(
        const float* __restrict__ x, const uint16_t* __restrict__ Wt,
        const float* __restrict__ bt, float* __restrict__ out) {
    const int tid = threadIdx.x;
    const int wave = tid >> 6, lane = tid & 63;
    const int quad = lane >> 4, l16 = lane & 15;
    const int mtile = blockIdx.x;
    // real col-tile count per wave (epilogue masking only): 4,4,4,4,4,4,2,0
    const int NT = (wave < 6) ? 4 : (wave == 6 ? 2 : 0);

    __shared__ __align__(16) char smem[SMEM_BYTES];
    uint16_t* As = (uint16_t*)smem;

    const float* xb = x + (size_t)mtile * 64 * KDIM;
    const int colbase = wave * 64;

    v4f acc[4][4];
    #pragma unroll
    for (int mi = 0; mi < 4; ++mi)
        #pragma unroll
        for (int ni = 0; ni < 4; ++ni)
            acc[mi][ni] = v4f{0.f, 0.f, 0.f, 0.f};

    const int am = tid >> 3, akc = tid & 7;        // A: row, float4-chunk
    const float* aptr = xb + (size_t)am * KDIM + akc * 4;          // +32 floats per kt

    // uniform B fragment pointers; out-of-range tiles clamp to tile 25 (dummy,
    // L2-hit loads; their accumulators are garbage and never stored)
    const uint16_t* bfrag[4];
    #pragma unroll
    for (int ni = 0; ni < 4; ++ni) {
        int t = wave * 4 + ni; if (t > 25) t = 25;
        bfrag[ni] = Wt + (size_t)(t * 16 + l16) * 32 + quad * 8;
    }

    v8s bcur[4];
    float4 av_n, av_nn;

    // ---- prologue: A(0) staged; A(1), A(2) and B(0) in flight
    {
        float4 av0 = *(const float4*)aptr;
        av_n  = *(const float4*)(aptr + 32);
        av_nn = *(const float4*)(aptr + 64);
        #pragma unroll
        for (int ni = 0; ni < 4; ++ni) bcur[ni] = *(const v8s*)bfrag[ni];
        stcvt(As + am * A_STRIDE + akc * 4, av0);
        asm volatile("s_waitcnt lgkmcnt(0)" ::: "memory");
        __builtin_amdgcn_s_barrier();
        asm volatile("" ::: "memory");
    }

    // ---- main loop: kt = 0..28, uniform body, 1 raw barrier/iter.
    // VMEM queue (oldest->newest) at iter kt: [A(kt+2), B(kt)x4, A(kt+3)]
    //   stcvt consumes A(kt+1): complete (2-iter cover), wait is a no-op
    //   first MFMA waits vmcnt(4) -> only B(kt) (L2, ~1 iter cover)
    int rb = 0;
    for (int kt = 0; kt < 29; ++kt) {
        const uint16_t* Ar = As + rb * A_BUF_ELEMS;
        v8s a0 = *(const v8s*)(Ar + (0 * 16 + l16) * A_STRIDE + quad * 8);
        v8s a1 = *(const v8s*)(Ar + (1 * 16 + l16) * A_STRIDE + quad * 8);
        v8s a2 = *(const v8s*)(Ar + (2 * 16 + l16) * A_STRIDE + quad * 8);
        v8s a3 = *(const v8s*)(Ar + (3 * 16 + l16) * A_STRIDE + quad * 8);
        stcvt(As + (rb ^ 1) * A_BUF_ELEMS + am * A_STRIDE + akc * 4, av_n);  // A(kt+1)
        av_n = av_nn;
        const size_t nxt = (size_t)(kt + 1) * SLAB;
        #pragma unroll
        for (int ni = 0; ni < 4; ++ni) {
            acc[0][ni] = __builtin_amdgcn_mfma_f32_16x16x32_bf16(a0, bcur[ni], acc[0][ni], 0, 0, 0);
            acc[1][ni] = __builtin_amdgcn_mfma_f32_16x16x32_bf16(a1, bcur[ni], acc[1][ni], 0, 0, 0);
            acc[2][ni] = __builtin_amdgcn_mfma_f32_16x16x32_bf16(a2, bcur[ni], acc[2][ni], 0, 0, 0);
            acc[3][ni] = __builtin_amdgcn_mfma_f32_16x16x32_bf16(a3, bcur[ni], acc[3][ni], 0, 0, 0);
            bcur[ni] = *(const v8s*)(bfrag[ni] + nxt);   // B(kt+1)
        }
        // pin the A prefetch AFTER the B loads in VMEM issue order
        __builtin_amdgcn_sched_barrier(0);
        av_nn = *(const float4*)(aptr + (size_t)(kt + 3) * 32);      // A(kt+3), newest
        asm volatile("s_waitcnt lgkmcnt(0)" ::: "memory");
        __builtin_amdgcn_s_barrier();
        asm volatile("" ::: "memory");
        rb ^= 1;
    }

    // ---- kt = 29 (peeled: no A prefetch)
    {
        const uint16_t* Ar = As + rb * A_BUF_ELEMS;
        v8s a0 = *(const v8s*)(Ar + (0 * 16 + l16) * A_STRIDE + quad * 8);
        v8s a1 = *(const v8s*)(Ar + (1 * 16 + l16) * A_STRIDE + quad * 8);
        v8s a2 = *(const v8s*)(Ar + (2 * 16 + l16) * A_STRIDE + quad * 8);
        v8s a3 = *(const v8s*)(Ar + (3 * 16 + l16) * A_STRIDE + quad * 8);
        stcvt(As + (rb ^ 1) * A_BUF_ELEMS + am * A_STRIDE + akc * 4, av_n);  // A(30)
        av_n = av_nn;
        const size_t nxt = (size_t)30 * SLAB;
        #pragma unroll
        for (int ni = 0; ni < 4; ++ni) {
            acc[0][ni] = __builtin_amdgcn_mfma_f32_16x16x32_bf16(a0, bcur[ni], acc[0][ni], 0, 0, 0);
            acc[1][ni] = __builtin_amdgcn_mfma_f32_16x16x32_bf16(a1, bcur[ni], acc[1][ni], 0, 0, 0);
            acc[2][ni] = __builtin_amdgcn_mfma_f32_16x16x32_bf16(a2, bcur[ni], acc[2][ni], 0, 0, 0);
            acc[3][ni] = __builtin_amdgcn_mfma_f32_16x16x32_bf16(a3, bcur[ni], acc[3][ni], 0, 0, 0);
            bcur[ni] = *(const v8s*)(bfrag[ni] + nxt);   // B(30)
        }
        asm volatile("s_waitcnt lgkmcnt(0)" ::: "memory");
        __builtin_amdgcn_s_barrier();
        asm volatile("" ::: "memory");
        rb ^= 1;
    }

    // ---- kt = 30 (peeled)
    {
        const uint16_t* Ar = As + rb * A_BUF_ELEMS;
        v8s a0 = *(const v8s*)(Ar + (0 * 16 + l16) * A_STRIDE + quad * 8);
        v8s a1 = *(const v8s*)(Ar + (1 * 16 + l16) * A_STRIDE + quad * 8);
        v8s a2 = *(const v8s*)(Ar + (2 * 16 + l16) * A_STRIDE + quad * 8);
        v8s a3 = *(const v8s*)(Ar + (3 * 16 + l16) * A_STRIDE + quad * 8);
        stcvt(As + (rb ^ 1) * A_BUF_ELEMS + am * A_STRIDE + akc * 4, av_n);  // A(31)
        const size_t nxt = (size_t)31 * SLAB;
        #pragma unroll
        for (int ni = 0; ni < 4; ++ni) {
            acc[0][ni] = __builtin_amdgcn_mfma_f32_16x16x32_bf16(a0, bcur[ni], acc[0][ni], 0, 0, 0);
            acc[1][ni] = __builtin_amdgcn_mfma_f32_16x16x32_bf16(a1, bcur[ni], acc[1][ni], 0, 0, 0);
            acc[2][ni] = __builtin_amdgcn_mfma_f32_16x16x32_bf16(a2, bcur[ni], acc[2][ni], 0, 0, 0);
            acc[3][ni] = __builtin_amdgcn_mfma_f32_16x16x32_bf16(a3, bcur[ni], acc[3][ni], 0, 0, 0);
            bcur[ni] = *(const v8s*)(bfrag[ni] + nxt);   // B(31)
        }
        asm volatile("s_waitcnt lgkmcnt(0)" ::: "memory");
        __builtin_amdgcn_s_barrier();
        asm volatile("" ::: "memory");
        rb ^= 1;
    }

    // ---- kt = 31 (peeled: compute only)
    {
        const uint16_t* Ar = As + rb * A_BUF_ELEMS;
        v8s a0 = *(const v8s*)(Ar + (0 * 16 + l16) * A_STRIDE + quad * 8);
        v8s a1 = *(const v8s*)(Ar + (1 * 16 + l16) * A_STRIDE + quad * 8);
        v8s a2 = *(const v8s*)(Ar + (2 * 16 + l16) * A_STRIDE + quad * 8);
        v8s a3 = *(const v8s*)(Ar + (3 * 16 + l16) * A_STRIDE + quad * 8);
        #pragma unroll
        for (int ni = 0; ni < 4; ++ni) {
            acc[0][ni] = __builtin_amdgcn_mfma_f32_16x16x32_bf16(a0, bcur[ni], acc[0][ni], 0, 0, 0);
            acc[1][ni] = __builtin_amdgcn_mfma_f32_16x16x32_bf16(a1, bcur[ni], acc[1][ni], 0, 0, 0);
            acc[2][ni] = __builtin_amdgcn_mfma_f32_16x16x32_bf16(a2, bcur[ni], acc[2][ni], 0, 0, 0);
            acc[3][ni] = __builtin_amdgcn_mfma_f32_16x16x32_bf16(a3, bcur[ni], acc[3][ni], 0, 0, 0);
        }
    }

    // ---- epilogue: stage through LDS (full-line coalesced, nontemporal stores)
    const int rowbase = mtile * 64;
    float* eps = (float*)smem;
    float* outb = out + (size_t)NROWS * SCORE_COLS;
    float bias[4];
    #pragma unroll
    for (int ni = 0; ni < 4; ++ni)
        bias[ni] = (ni < NT) ? bt[colbase + ni * 16 + l16] : 0.f;
    #pragma unroll
    for (int h = 0; h < 2; ++h) {
        __syncthreads();                       // LDS free for reuse / prev half done
        #pragma unroll
        for (int mi2 = 0; mi2 < 2; ++mi2) {
            const int mi = h * 2 + mi2;
            #pragma unroll
            for (int ni = 0; ni < 4; ++ni) {
                const int col = colbase + ni * 16 + l16;
                if (ni < NT && col < NCOLS) {
                    #pragma unroll
                    for (int r = 0; r < 4; ++r)
                        eps[(mi2 * 16 + quad * 4 + r) * EPS_STRIDE + col] = acc[mi][ni][r] + bias[ni];
                }
            }
        }
        __syncthreads();
        const int row0 = rowbase + h * 32;
        for (int idx = tid; idx < 32 * SCORE_COLS; idx += 512) {
            int r = idx / SCORE_COLS, c = idx - r * SCORE_COLS;
            __builtin_nontemporal_store(eps[r * EPS_STRIDE + c],
                                        &out[(size_t)(row0 + r) * SCORE_COLS + c]);
        }
        for (int idx = tid; idx < 32 * BBOX_COLS; idx += 512) {
            int r = idx / BBOX_COLS, c = idx - r * BBOX_COLS;
            __builtin_nontemporal_store(eps[r * EPS_STRIDE + SCORE_COLS + c],
                                        &outb[(size_t)(row0 + r) * BBOX_COLS + c]);
        }
    }
}

extern "C" void kernel_launch(void* const* d_in, const int* in_sizes, int n_in,
                              void* d_out, int out_size, void* d_ws, size_t ws_size,
                              hipStream_t stream) {
    const float* x     = (const float*)d_in[0];
    const float* Wcls  = (const float*)d_in[1];
    const float* bcls  = (const float*)d_in[2];
    const float* Wsem  = (const float*)d_in[3];
    const float* bsem  = (const float*)d_in[4];
    const float* Wbbox = (const float*)d_in[5];
    const float* bbbox = (const float*)d_in[6];
    const float* semm  = (const float*)d_in[7];
    float* out = (float*)d_out;

    uint16_t* Wt = (uint16_t*)d_ws;                                  // 416*1024*2 = 832 KB (blocked)
    float*    bt = (float*)((char*)d_ws + (size_t)NPAD * KDIM * 2);  // 1.7 KB

    fill_w<<<dim3((NPAD * KDIM) / 256), dim3(256), 0, stream>>>(Wcls, bcls, Wbbox, bbbox, Wt, bt);
    fill_w_sem<<<dim3(80, 4), dim3(256), 0, stream>>>(Wsem, bsem, semm, Wt, bt);
    gemm_fused<<<dim3(NROWS / 64), dim3(512), 0, stream>>>(x, Wt, bt, out);
}